// Round 3
// baseline (554.461 us; speedup 1.0000x reference)
//
#include <hip/hip_runtime.h>
#include <hip/hip_bf16.h>
#include <cstddef>

#define B_ 4096
#define D_ 4000
#define K_ 6
#define Z_ 64
#define DV_ 1000    // D/4 vec-columns per row
#define HALF_ 500   // vec-columns per block (row split in 2)
#define GRID_ (B_ * 2)
#define EPS_ 1e-8f

typedef float f32x4 __attribute__((ext_vector_type(4)));
typedef float f32x2 __attribute__((ext_vector_type(2)));

// lgamma for x in (0, ~2]: lgamma(x) = stirling(x+4) - log(x(x+1)(x+2)(x+3))
__device__ __forceinline__ float lgamma_small(float x) {
    float y = x + 4.0f;
    float p = x * (x + 1.0f) * (x + 2.0f) * (x + 3.0f);
    float ly = __logf(y);
    float r = 1.0f / y;
    float corr = r * (0.08333333333f - 0.002777777778f * (r * r));
    float stir = (y - 0.5f) * ly - y + 0.91893853320467f + corr;
    return stir - __logf(p);
}

__device__ __forceinline__ void elem(float xv, float mg, float mn, float tv,
                                     float xiv, float qv, int mk,
                                     float n0, float n1, float n2,
                                     float n3, float n4, float n5,
                                     float& s_nll, float& s_sp) {
    float nbm = (n0 + n1 + n2 + n3 + n4 + n5) * (1.0f / 6.0f);
    float d = qv - (xiv - nbm);
    s_sp += d * d;
    float gd = xv - mg;
    float g = 0.5f * gd * gd;
    float ltme = __logf(tv + mn + EPS_);
    float ll = tv * (__logf(tv + EPS_) - ltme)
             + xv * (__logf(mn + EPS_) - ltme)
             + lgamma_small(xv + tv) - lgamma_small(tv) - lgamma_small(xv + 1.0f);
    s_nll += mk ? g : -ll;
}

#define NTL(p) __builtin_nontemporal_load(&(p))

__global__ __launch_bounds__(256) void fused_row_kernel(
    const f32x4* __restrict__ x, const f32x4* __restrict__ mug,
    const f32x4* __restrict__ munb, const f32x4* __restrict__ th,
    const f32x4* __restrict__ xi, const f32x4* __restrict__ qy,
    const f32x4* __restrict__ nb, const int4* __restrict__ mask,
    const f32x2* __restrict__ muz, const f32x2* __restrict__ lvz,
    const f32x2* __restrict__ epz, f32x2* __restrict__ z,
    f32x2* __restrict__ partial, unsigned* __restrict__ counter,
    float* __restrict__ out)
{
    const int b = blockIdx.x;
    const int tid = threadIdx.x;
    const int row = b >> 1;
    const int h = b & 1;
    const size_t rowv = (size_t)row * DV_ + (size_t)h * HALF_;
    const f32x4* nbrow = nb + (size_t)row * (K_ * DV_) + (size_t)h * HALF_;

    // reparametrize slice: 16 float2 per block (8192*16 = 131072 = B*Z/2)
    if (tid < 16) {
        const int i = b * 16 + tid;
        f32x2 m = NTL(muz[i]), l = NTL(lvz[i]), e = NTL(epz[i]);
        f32x2 r;
        r.x = m.x + e.x * __expf(0.5f * l.x);
        r.y = m.y + e.y * __expf(0.5f * l.y);
        __builtin_nontemporal_store(r, &z[i]);
    }

    float s_nll = 0.0f, s_sp = 0.0f;

    for (int j = tid; j < HALF_; j += 256) {
        f32x4 xv  = NTL(x[rowv + j]);
        f32x4 mg  = NTL(mug[rowv + j]);
        f32x4 mn  = NTL(munb[rowv + j]);
        f32x4 tv  = NTL(th[rowv + j]);
        f32x4 xiv = NTL(xi[rowv + j]);
        f32x4 qv  = NTL(qy[rowv + j]);
        int4   mk = mask[h * HALF_ + j];     // reused by all blocks: keep cached
        f32x4 n0 = NTL(nbrow[0 * DV_ + j]);
        f32x4 n1 = NTL(nbrow[1 * DV_ + j]);
        f32x4 n2 = NTL(nbrow[2 * DV_ + j]);
        f32x4 n3 = NTL(nbrow[3 * DV_ + j]);
        f32x4 n4 = NTL(nbrow[4 * DV_ + j]);
        f32x4 n5 = NTL(nbrow[5 * DV_ + j]);

        elem(xv.x, mg.x, mn.x, tv.x, xiv.x, qv.x, mk.x, n0.x, n1.x, n2.x, n3.x, n4.x, n5.x, s_nll, s_sp);
        elem(xv.y, mg.y, mn.y, tv.y, xiv.y, qv.y, mk.y, n0.y, n1.y, n2.y, n3.y, n4.y, n5.y, s_nll, s_sp);
        elem(xv.z, mg.z, mn.z, tv.z, xiv.z, qv.z, mk.z, n0.z, n1.z, n2.z, n3.z, n4.z, n5.z, s_nll, s_sp);
        elem(xv.w, mg.w, mn.w, tv.w, xiv.w, qv.w, mk.w, n0.w, n1.w, n2.w, n3.w, n4.w, n5.w, s_nll, s_sp);
    }

    // wave64 reduce
    for (int off = 32; off > 0; off >>= 1) {
        s_nll += __shfl_down(s_nll, off, 64);
        s_sp  += __shfl_down(s_sp,  off, 64);
    }
    __shared__ float sa[4], sb[4];
    __shared__ int is_last;
    const int lane = tid & 63;
    const int w    = tid >> 6;
    if (lane == 0) { sa[w] = s_nll; sb[w] = s_sp; }
    __syncthreads();
    if (tid == 0) {
        f32x2 o;
        o.x = sa[0] + sa[1] + sa[2] + sa[3];
        o.y = sb[0] + sb[1] + sb[2] + sb[3];
        partial[b] = o;
        __threadfence();                       // make partial visible device-wide
        unsigned t = atomicAdd(counter, 1u);
        is_last = (t == GRID_ - 1u) ? 1 : 0;
    }
    __syncthreads();

    if (is_last) {
        // deterministic final reduce: fixed index order, double accumulation
        const float* pp = (const float*)partial;
        double a = 0.0, bb = 0.0;
        for (int i = tid; i < GRID_; i += 256) {
            float px = __hip_atomic_load(pp + 2 * i,     __ATOMIC_RELAXED, __HIP_MEMORY_SCOPE_AGENT);
            float py = __hip_atomic_load(pp + 2 * i + 1, __ATOMIC_RELAXED, __HIP_MEMORY_SCOPE_AGENT);
            a += (double)px;
            bb += (double)py;
        }
        __shared__ double da[256], db[256];
        da[tid] = a; db[tid] = bb;
        __syncthreads();
        for (int s = 128; s > 0; s >>= 1) {
            if (tid < s) { da[tid] += da[tid + s]; db[tid] += db[tid + s]; }
            __syncthreads();
        }
        if (tid == 0) {
            out[0] = (float)(da[0] / (double)B_);
            out[1] = (float)(db[0] / ((double)B_ * (double)D_));
        }
    }
}

extern "C" void kernel_launch(void* const* d_in, const int* in_sizes, int n_in,
                              void* d_out, int out_size, void* d_ws, size_t ws_size,
                              hipStream_t stream) {
    const f32x4* x    = (const f32x4*)d_in[0];
    const f32x4* mug  = (const f32x4*)d_in[1];
    // d_in[2] = logvar_gauss, unused by the reference
    const f32x4* munb = (const f32x4*)d_in[3];
    const f32x4* th   = (const f32x4*)d_in[4];
    const f32x4* xi   = (const f32x4*)d_in[5];
    const f32x4* nb   = (const f32x4*)d_in[6];
    const f32x4* qy   = (const f32x4*)d_in[7];
    const f32x2* muz  = (const f32x2*)d_in[8];
    const f32x2* lvz  = (const f32x2*)d_in[9];
    const f32x2* epz  = (const f32x2*)d_in[10];
    const int4*  mask = (const int4*)d_in[11];

    float* out = (float*)d_out;
    unsigned* counter = (unsigned*)d_ws;                 // 4 bytes, zeroed below
    f32x2* partial = (f32x2*)((char*)d_ws + 16);         // GRID_ float2 = 64 KB
    f32x2* z = (f32x2*)(out + 2);

    hipMemsetAsync(counter, 0, sizeof(unsigned), stream);
    fused_row_kernel<<<GRID_, 256, 0, stream>>>(x, mug, munb, th, xi, qy, nb, mask,
                                                muz, lvz, epz, z, partial, counter, out);
}

// Round 4
// 166.376 us; speedup vs baseline: 3.3326x; 3.3326x over previous
//
#include <hip/hip_runtime.h>
#include <hip/hip_bf16.h>
#include <cstddef>

#define B_ 4096
#define D_ 4000
#define K_ 6
#define Z_ 64
#define DV_ 1000    // D/4 vec-columns per row
#define HALF_ 500   // vec-columns per block (row split in 2)
#define GRID_ (B_ * 2)
#define EPS_ 1e-8f

typedef float f32x4 __attribute__((ext_vector_type(4)));
typedef float f32x2 __attribute__((ext_vector_type(2)));

// lgamma for x in (0, ~2]: lgamma(x) = stirling(x+4) - log(x(x+1)(x+2)(x+3))
__device__ __forceinline__ float lgamma_small(float x) {
    float y = x + 4.0f;
    float p = x * (x + 1.0f) * (x + 2.0f) * (x + 3.0f);
    float ly = __logf(y);
    float r = 1.0f / y;
    float corr = r * (0.08333333333f - 0.002777777778f * (r * r));
    float stir = (y - 0.5f) * ly - y + 0.91893853320467f + corr;
    return stir - __logf(p);
}

__device__ __forceinline__ void elem(float xv, float mg, float mn, float tv,
                                     float xiv, float qv, int mk,
                                     float n0, float n1, float n2,
                                     float n3, float n4, float n5,
                                     float& s_nll, float& s_sp) {
    float nbm = (n0 + n1 + n2 + n3 + n4 + n5) * (1.0f / 6.0f);
    float d = qv - (xiv - nbm);
    s_sp += d * d;
    float gd = xv - mg;
    float g = 0.5f * gd * gd;
    float ltme = __logf(tv + mn + EPS_);
    float ll = tv * (__logf(tv + EPS_) - ltme)
             + xv * (__logf(mn + EPS_) - ltme)
             + lgamma_small(xv + tv) - lgamma_small(tv) - lgamma_small(xv + 1.0f);
    s_nll += mk ? g : -ll;
}

#define NTL(p) __builtin_nontemporal_load(&(p))

__global__ __launch_bounds__(256) void fused_row_kernel(
    const f32x4* __restrict__ x, const f32x4* __restrict__ mug,
    const f32x4* __restrict__ munb, const f32x4* __restrict__ th,
    const f32x4* __restrict__ xi, const f32x4* __restrict__ qy,
    const f32x4* __restrict__ nb, const int4* __restrict__ mask,
    const f32x2* __restrict__ muz, const f32x2* __restrict__ lvz,
    const f32x2* __restrict__ epz, f32x2* __restrict__ z,
    f32x2* __restrict__ partial, unsigned* __restrict__ counter,
    float* __restrict__ out)
{
    const int b = blockIdx.x;
    const int tid = threadIdx.x;
    const int row = b >> 1;
    const int h = b & 1;
    const size_t rowv = (size_t)row * DV_ + (size_t)h * HALF_;
    const f32x4* nbrow = nb + (size_t)row * (K_ * DV_) + (size_t)h * HALF_;

    // reparametrize slice: 16 float2 per block (8192*16 = 131072 = B*Z/2)
    if (tid < 16) {
        const int i = b * 16 + tid;
        f32x2 m = NTL(muz[i]), l = NTL(lvz[i]), e = NTL(epz[i]);
        f32x2 r;
        r.x = m.x + e.x * __expf(0.5f * l.x);
        r.y = m.y + e.y * __expf(0.5f * l.y);
        __builtin_nontemporal_store(r, &z[i]);
    }

    float s_nll = 0.0f, s_sp = 0.0f;

    for (int j = tid; j < HALF_; j += 256) {
        f32x4 xv  = NTL(x[rowv + j]);
        f32x4 mg  = NTL(mug[rowv + j]);
        f32x4 mn  = NTL(munb[rowv + j]);
        f32x4 tv  = NTL(th[rowv + j]);
        f32x4 xiv = NTL(xi[rowv + j]);
        f32x4 qv  = NTL(qy[rowv + j]);
        int4   mk = mask[h * HALF_ + j];     // reused by all blocks: keep cached
        f32x4 n0 = NTL(nbrow[0 * DV_ + j]);
        f32x4 n1 = NTL(nbrow[1 * DV_ + j]);
        f32x4 n2 = NTL(nbrow[2 * DV_ + j]);
        f32x4 n3 = NTL(nbrow[3 * DV_ + j]);
        f32x4 n4 = NTL(nbrow[4 * DV_ + j]);
        f32x4 n5 = NTL(nbrow[5 * DV_ + j]);

        elem(xv.x, mg.x, mn.x, tv.x, xiv.x, qv.x, mk.x, n0.x, n1.x, n2.x, n3.x, n4.x, n5.x, s_nll, s_sp);
        elem(xv.y, mg.y, mn.y, tv.y, xiv.y, qv.y, mk.y, n0.y, n1.y, n2.y, n3.y, n4.y, n5.y, s_nll, s_sp);
        elem(xv.z, mg.z, mn.z, tv.z, xiv.z, qv.z, mk.z, n0.z, n1.z, n2.z, n3.z, n4.z, n5.z, s_nll, s_sp);
        elem(xv.w, mg.w, mn.w, tv.w, xiv.w, qv.w, mk.w, n0.w, n1.w, n2.w, n3.w, n4.w, n5.w, s_nll, s_sp);
    }

    // wave64 reduce
    for (int off = 32; off > 0; off >>= 1) {
        s_nll += __shfl_down(s_nll, off, 64);
        s_sp  += __shfl_down(s_sp,  off, 64);
    }
    __shared__ float sa[4], sb[4];
    __shared__ int is_last;
    const int lane = tid & 63;
    const int w    = tid >> 6;
    if (lane == 0) { sa[w] = s_nll; sb[w] = s_sp; }
    __syncthreads();
    if (tid == 0) {
        union { f32x2 f; unsigned long long u; } pun;
        pun.f.x = sa[0] + sa[1] + sa[2] + sa[3];
        pun.f.y = sb[0] + sb[1] + sb[2] + sb[3];
        // Fence-free release: agent-scope relaxed atomic store (sc1 write-through,
        // no L2 writeback), manual vmcnt drain to order store -> counter RMW.
        __hip_atomic_store((unsigned long long*)&partial[b], pun.u,
                           __ATOMIC_RELAXED, __HIP_MEMORY_SCOPE_AGENT);
        asm volatile("s_waitcnt vmcnt(0)" ::: "memory");
        unsigned t = __hip_atomic_fetch_add(counter, 1u,
                                            __ATOMIC_RELAXED, __HIP_MEMORY_SCOPE_AGENT);
        is_last = (t == GRID_ - 1u) ? 1 : 0;
    }
    __syncthreads();

    if (is_last) {
        // deterministic final reduce: fixed index order, double accumulation
        unsigned long long* pp = (unsigned long long*)partial;
        double a = 0.0, bb = 0.0;
        for (int i = tid; i < GRID_; i += 256) {
            unsigned long long v = __hip_atomic_load(pp + i, __ATOMIC_RELAXED,
                                                     __HIP_MEMORY_SCOPE_AGENT);
            union { unsigned long long u; f32x2 f; } pun; pun.u = v;
            a += (double)pun.f.x;
            bb += (double)pun.f.y;
        }
        __shared__ double da[256], db[256];
        da[tid] = a; db[tid] = bb;
        __syncthreads();
        for (int s = 128; s > 0; s >>= 1) {
            if (tid < s) { da[tid] += da[tid + s]; db[tid] += db[tid + s]; }
            __syncthreads();
        }
        if (tid == 0) {
            out[0] = (float)(da[0] / (double)B_);
            out[1] = (float)(db[0] / ((double)B_ * (double)D_));
        }
    }
}

extern "C" void kernel_launch(void* const* d_in, const int* in_sizes, int n_in,
                              void* d_out, int out_size, void* d_ws, size_t ws_size,
                              hipStream_t stream) {
    const f32x4* x    = (const f32x4*)d_in[0];
    const f32x4* mug  = (const f32x4*)d_in[1];
    // d_in[2] = logvar_gauss, unused by the reference
    const f32x4* munb = (const f32x4*)d_in[3];
    const f32x4* th   = (const f32x4*)d_in[4];
    const f32x4* xi   = (const f32x4*)d_in[5];
    const f32x4* nb   = (const f32x4*)d_in[6];
    const f32x4* qy   = (const f32x4*)d_in[7];
    const f32x2* muz  = (const f32x2*)d_in[8];
    const f32x2* lvz  = (const f32x2*)d_in[9];
    const f32x2* epz  = (const f32x2*)d_in[10];
    const int4*  mask = (const int4*)d_in[11];

    float* out = (float*)d_out;
    unsigned* counter = (unsigned*)d_ws;                 // 4 bytes, zeroed below
    f32x2* partial = (f32x2*)((char*)d_ws + 16);         // GRID_ float2 = 64 KB
    f32x2* z = (f32x2*)(out + 2);

    hipMemsetAsync(counter, 0, sizeof(unsigned), stream);
    fused_row_kernel<<<GRID_, 256, 0, stream>>>(x, mug, munb, th, xi, qy, nb, mask,
                                                muz, lvz, epz, z, partial, counter, out);
}

// Round 5
// 145.787 us; speedup vs baseline: 3.8032x; 1.1412x over previous
//
#include <hip/hip_runtime.h>
#include <hip/hip_bf16.h>
#include <cstddef>

#define B_ 4096
#define D_ 4000
#define K_ 6
#define Z_ 64
#define DV_ 1000   // D/4 vec-columns per row
#define EPS_ 1e-8f

typedef float f32x4 __attribute__((ext_vector_type(4)));
typedef float f32x2 __attribute__((ext_vector_type(2)));

// lgamma for x in (0, ~2]: lgamma(x) = stirling(x+4) - log(x(x+1)(x+2)(x+3))
__device__ __forceinline__ float lgamma_small(float x) {
    float y = x + 4.0f;
    float p = x * (x + 1.0f) * (x + 2.0f) * (x + 3.0f);
    float ly = __logf(y);
    float r = 1.0f / y;
    float corr = r * (0.08333333333f - 0.002777777778f * (r * r));
    float stir = (y - 0.5f) * ly - y + 0.91893853320467f + corr;
    return stir - __logf(p);
}

__device__ __forceinline__ void elem(float xv, float mg, float mn, float tv,
                                     float xiv, float qv, int mk,
                                     float n0, float n1, float n2,
                                     float n3, float n4, float n5,
                                     float& s_nll, float& s_sp) {
    float nbm = (n0 + n1 + n2 + n3 + n4 + n5) * (1.0f / 6.0f);
    float d = qv - (xiv - nbm);
    s_sp += d * d;
    float gd = xv - mg;
    float g = 0.5f * gd * gd;
    float ltme = __logf(tv + mn + EPS_);
    float ll = tv * (__logf(tv + EPS_) - ltme)
             + xv * (__logf(mn + EPS_) - ltme)
             + lgamma_small(xv + tv) - lgamma_small(tv) - lgamma_small(xv + 1.0f);
    s_nll += mk ? g : -ll;
}

#define NTL(p) __builtin_nontemporal_load(&(p))

__global__ __launch_bounds__(256) void fused_row_kernel(
    const f32x4* __restrict__ x, const f32x4* __restrict__ mug,
    const f32x4* __restrict__ munb, const f32x4* __restrict__ th,
    const f32x4* __restrict__ xi, const f32x4* __restrict__ qy,
    const f32x4* __restrict__ nb, const int4* __restrict__ mask,
    const f32x2* __restrict__ muz, const f32x2* __restrict__ lvz,
    const f32x2* __restrict__ epz, f32x2* __restrict__ z,
    f32x2* __restrict__ partial)
{
    const int b = blockIdx.x;
    const int tid = threadIdx.x;
    const size_t rowv = (size_t)b * DV_;
    const f32x4* nbrow = nb + (size_t)b * (K_ * DV_);

    // reparametrize slice: 32 float2 per block (4096*32 = 131072 = B*Z/2)
    if (tid < 32) {
        const int i = b * 32 + tid;
        f32x2 m = NTL(muz[i]), l = NTL(lvz[i]), e = NTL(epz[i]);
        f32x2 r;
        r.x = m.x + e.x * __expf(0.5f * l.x);
        r.y = m.y + e.y * __expf(0.5f * l.y);
        __builtin_nontemporal_store(r, &z[i]);
    }

    float s_nll = 0.0f, s_sp = 0.0f;

    // Fixed 4-slot mapping: j = tid + {0,256,512} always valid (tid+512 <= 767
    // < 1000); j = tid+768 valid for tid < 232. Full unroll -> 36-48
    // outstanding 16B loads per thread for deep MLP.
#define BODY(J)                                                                \
    {                                                                          \
        const int j = (J);                                                     \
        f32x4 n0 = NTL(nbrow[0 * DV_ + j]);                                    \
        f32x4 n1 = NTL(nbrow[1 * DV_ + j]);                                    \
        f32x4 n2 = NTL(nbrow[2 * DV_ + j]);                                    \
        f32x4 n3 = NTL(nbrow[3 * DV_ + j]);                                    \
        f32x4 n4 = NTL(nbrow[4 * DV_ + j]);                                    \
        f32x4 n5 = NTL(nbrow[5 * DV_ + j]);                                    \
        f32x4 xv  = NTL(x[rowv + j]);                                          \
        f32x4 mg  = NTL(mug[rowv + j]);                                        \
        f32x4 mn  = NTL(munb[rowv + j]);                                       \
        f32x4 tv  = NTL(th[rowv + j]);                                         \
        f32x4 xiv = NTL(xi[rowv + j]);                                         \
        f32x4 qv  = NTL(qy[rowv + j]);                                         \
        int4   mk = mask[j];                                                   \
        elem(xv.x, mg.x, mn.x, tv.x, xiv.x, qv.x, mk.x,                        \
             n0.x, n1.x, n2.x, n3.x, n4.x, n5.x, s_nll, s_sp);                 \
        elem(xv.y, mg.y, mn.y, tv.y, xiv.y, qv.y, mk.y,                        \
             n0.y, n1.y, n2.y, n3.y, n4.y, n5.y, s_nll, s_sp);                 \
        elem(xv.z, mg.z, mn.z, tv.z, xiv.z, qv.z, mk.z,                        \
             n0.z, n1.z, n2.z, n3.z, n4.z, n5.z, s_nll, s_sp);                 \
        elem(xv.w, mg.w, mn.w, tv.w, xiv.w, qv.w, mk.w,                        \
             n0.w, n1.w, n2.w, n3.w, n4.w, n5.w, s_nll, s_sp);                 \
    }

    BODY(tid)
    BODY(tid + 256)
    BODY(tid + 512)
    if (tid < DV_ - 768) BODY(tid + 768)
#undef BODY

    // wave64 reduce
    for (int off = 32; off > 0; off >>= 1) {
        s_nll += __shfl_down(s_nll, off, 64);
        s_sp  += __shfl_down(s_sp,  off, 64);
    }
    __shared__ float sa[4], sb[4];
    const int lane = tid & 63;
    const int w    = tid >> 6;
    if (lane == 0) { sa[w] = s_nll; sb[w] = s_sp; }
    __syncthreads();
    if (tid == 0) {
        f32x2 o;
        o.x = sa[0] + sa[1] + sa[2] + sa[3];
        o.y = sb[0] + sb[1] + sb[2] + sb[3];
        partial[b] = o;
    }
}

__global__ __launch_bounds__(256) void finalize_kernel(
    const f32x2* __restrict__ partial, float* __restrict__ out)
{
    __shared__ double sa[256], sb[256];
    double a = 0.0, b = 0.0;
    for (int i = threadIdx.x; i < B_; i += 256) {
        f32x2 p = partial[i];
        a += (double)p.x;
        b += (double)p.y;
    }
    sa[threadIdx.x] = a; sb[threadIdx.x] = b;
    __syncthreads();
    for (int s = 128; s > 0; s >>= 1) {
        if (threadIdx.x < s) {
            sa[threadIdx.x] += sa[threadIdx.x + s];
            sb[threadIdx.x] += sb[threadIdx.x + s];
        }
        __syncthreads();
    }
    if (threadIdx.x == 0) {
        out[0] = (float)(sa[0] / (double)B_);
        out[1] = (float)(sb[0] / ((double)B_ * (double)D_));
    }
}

extern "C" void kernel_launch(void* const* d_in, const int* in_sizes, int n_in,
                              void* d_out, int out_size, void* d_ws, size_t ws_size,
                              hipStream_t stream) {
    const f32x4* x    = (const f32x4*)d_in[0];
    const f32x4* mug  = (const f32x4*)d_in[1];
    // d_in[2] = logvar_gauss, unused by the reference
    const f32x4* munb = (const f32x4*)d_in[3];
    const f32x4* th   = (const f32x4*)d_in[4];
    const f32x4* xi   = (const f32x4*)d_in[5];
    const f32x4* nb   = (const f32x4*)d_in[6];
    const f32x4* qy   = (const f32x4*)d_in[7];
    const f32x2* muz  = (const f32x2*)d_in[8];
    const f32x2* lvz  = (const f32x2*)d_in[9];
    const f32x2* epz  = (const f32x2*)d_in[10];
    const int4*  mask = (const int4*)d_in[11];

    float* out = (float*)d_out;
    f32x2* partial = (f32x2*)d_ws;
    f32x2* z = (f32x2*)(out + 2);

    fused_row_kernel<<<B_, 256, 0, stream>>>(x, mug, munb, th, xi, qy, nb, mask,
                                             muz, lvz, epz, z, partial);
    finalize_kernel<<<1, 256, 0, stream>>>(partial, out);
}

// Round 6
// 138.233 us; speedup vs baseline: 4.0111x; 1.0546x over previous
//
#include <hip/hip_runtime.h>
#include <hip/hip_bf16.h>
#include <cstddef>

#define B_ 4096
#define D_ 4000
#define K_ 6
#define Z_ 64
#define DV_ 1000    // D/4 vec-columns per row
#define HALF_ 500   // vec-columns per block (row split in 2)
#define GRID_ (B_ * 2)
#define EPS_ 1e-8f

typedef float f32x4 __attribute__((ext_vector_type(4)));
typedef float f32x2 __attribute__((ext_vector_type(2)));

// lgamma for x in (0, ~2]: lgamma(x) = stirling(x+4) - log(x(x+1)(x+2)(x+3))
__device__ __forceinline__ float lgamma_small(float x) {
    float y = x + 4.0f;
    float p = x * (x + 1.0f) * (x + 2.0f) * (x + 3.0f);
    float ly = __logf(y);
    float r = 1.0f / y;
    float corr = r * (0.08333333333f - 0.002777777778f * (r * r));
    float stir = (y - 0.5f) * ly - y + 0.91893853320467f + corr;
    return stir - __logf(p);
}

__device__ __forceinline__ void elem(float xv, float mg, float mn, float tv,
                                     float xiv, float qv, int mk,
                                     float n0, float n1, float n2,
                                     float n3, float n4, float n5,
                                     float& s_nll, float& s_sp) {
    float nbm = (n0 + n1 + n2 + n3 + n4 + n5) * (1.0f / 6.0f);
    float d = qv - (xiv - nbm);
    s_sp += d * d;
    float gd = xv - mg;
    float g = 0.5f * gd * gd;
    float ltme = __logf(tv + mn + EPS_);
    float ll = tv * (__logf(tv + EPS_) - ltme)
             + xv * (__logf(mn + EPS_) - ltme)
             + lgamma_small(xv + tv) - lgamma_small(tv) - lgamma_small(xv + 1.0f);
    s_nll += mk ? g : -ll;
}

#define NTL(p) __builtin_nontemporal_load(&(p))

__global__ __launch_bounds__(256) void fused_row_kernel(
    const f32x4* __restrict__ x, const f32x4* __restrict__ mug,
    const f32x4* __restrict__ munb, const f32x4* __restrict__ th,
    const f32x4* __restrict__ xi, const f32x4* __restrict__ qy,
    const f32x4* __restrict__ nb, const int4* __restrict__ mask,
    const f32x2* __restrict__ muz, const f32x2* __restrict__ lvz,
    const f32x2* __restrict__ epz, f32x2* __restrict__ z,
    f32x2* __restrict__ partial)
{
    const int b = blockIdx.x;
    const int tid = threadIdx.x;
    const int row = b >> 1;
    const int h = b & 1;
    const size_t rowv = (size_t)row * DV_ + (size_t)h * HALF_;
    const f32x4* nbrow = nb + (size_t)row * (K_ * DV_) + (size_t)h * HALF_;

    // reparametrize slice: 16 float2 per block (8192*16 = 131072 = B*Z/2)
    if (tid < 16) {
        const int i = b * 16 + tid;
        f32x2 m = NTL(muz[i]), l = NTL(lvz[i]), e = NTL(epz[i]);
        f32x2 r;
        r.x = m.x + e.x * __expf(0.5f * l.x);
        r.y = m.y + e.y * __expf(0.5f * l.y);
        __builtin_nontemporal_store(r, &z[i]);
    }

    float s_nll = 0.0f, s_sp = 0.0f;

    for (int j = tid; j < HALF_; j += 256) {
        f32x4 xv  = NTL(x[rowv + j]);
        f32x4 mg  = NTL(mug[rowv + j]);
        f32x4 mn  = NTL(munb[rowv + j]);
        f32x4 tv  = NTL(th[rowv + j]);
        f32x4 xiv = NTL(xi[rowv + j]);
        f32x4 qv  = NTL(qy[rowv + j]);
        int4   mk = mask[h * HALF_ + j];     // reused by all blocks: keep cached
        f32x4 n0 = NTL(nbrow[0 * DV_ + j]);
        f32x4 n1 = NTL(nbrow[1 * DV_ + j]);
        f32x4 n2 = NTL(nbrow[2 * DV_ + j]);
        f32x4 n3 = NTL(nbrow[3 * DV_ + j]);
        f32x4 n4 = NTL(nbrow[4 * DV_ + j]);
        f32x4 n5 = NTL(nbrow[5 * DV_ + j]);

        elem(xv.x, mg.x, mn.x, tv.x, xiv.x, qv.x, mk.x, n0.x, n1.x, n2.x, n3.x, n4.x, n5.x, s_nll, s_sp);
        elem(xv.y, mg.y, mn.y, tv.y, xiv.y, qv.y, mk.y, n0.y, n1.y, n2.y, n3.y, n4.y, n5.y, s_nll, s_sp);
        elem(xv.z, mg.z, mn.z, tv.z, xiv.z, qv.z, mk.z, n0.z, n1.z, n2.z, n3.z, n4.z, n5.z, s_nll, s_sp);
        elem(xv.w, mg.w, mn.w, tv.w, xiv.w, qv.w, mk.w, n0.w, n1.w, n2.w, n3.w, n4.w, n5.w, s_nll, s_sp);
    }

    // wave64 reduce
    for (int off = 32; off > 0; off >>= 1) {
        s_nll += __shfl_down(s_nll, off, 64);
        s_sp  += __shfl_down(s_sp,  off, 64);
    }
    __shared__ float sa[4], sb[4];
    const int lane = tid & 63;
    const int w    = tid >> 6;
    if (lane == 0) { sa[w] = s_nll; sb[w] = s_sp; }
    __syncthreads();
    if (tid == 0) {
        f32x2 o;
        o.x = sa[0] + sa[1] + sa[2] + sa[3];
        o.y = sb[0] + sb[1] + sb[2] + sb[3];
        partial[b] = o;
    }
}

__global__ __launch_bounds__(256) void finalize_kernel(
    const f32x2* __restrict__ partial, float* __restrict__ out)
{
    __shared__ double sa[256], sb[256];
    double a = 0.0, b = 0.0;
    for (int i = threadIdx.x; i < GRID_; i += 256) {
        f32x2 p = partial[i];
        a += (double)p.x;
        b += (double)p.y;
    }
    sa[threadIdx.x] = a; sb[threadIdx.x] = b;
    __syncthreads();
    for (int s = 128; s > 0; s >>= 1) {
        if (threadIdx.x < s) {
            sa[threadIdx.x] += sa[threadIdx.x + s];
            sb[threadIdx.x] += sb[threadIdx.x + s];
        }
        __syncthreads();
    }
    if (threadIdx.x == 0) {
        out[0] = (float)(sa[0] / (double)B_);
        out[1] = (float)(sb[0] / ((double)B_ * (double)D_));
    }
}

extern "C" void kernel_launch(void* const* d_in, const int* in_sizes, int n_in,
                              void* d_out, int out_size, void* d_ws, size_t ws_size,
                              hipStream_t stream) {
    const f32x4* x    = (const f32x4*)d_in[0];
    const f32x4* mug  = (const f32x4*)d_in[1];
    // d_in[2] = logvar_gauss, unused by the reference
    const f32x4* munb = (const f32x4*)d_in[3];
    const f32x4* th   = (const f32x4*)d_in[4];
    const f32x4* xi   = (const f32x4*)d_in[5];
    const f32x4* nb   = (const f32x4*)d_in[6];
    const f32x4* qy   = (const f32x4*)d_in[7];
    const f32x2* muz  = (const f32x2*)d_in[8];
    const f32x2* lvz  = (const f32x2*)d_in[9];
    const f32x2* epz  = (const f32x2*)d_in[10];
    const int4*  mask = (const int4*)d_in[11];

    float* out = (float*)d_out;
    f32x2* partial = (f32x2*)d_ws;
    f32x2* z = (f32x2*)(out + 2);

    fused_row_kernel<<<GRID_, 256, 0, stream>>>(x, mug, munb, th, xi, qy, nb, mask,
                                                muz, lvz, epz, z, partial);
    finalize_kernel<<<1, 256, 0, stream>>>(partial, out);
}

// Round 7
// 132.812 us; speedup vs baseline: 4.1748x; 1.0408x over previous
//
#include <hip/hip_runtime.h>
#include <hip/hip_bf16.h>
#include <cstddef>

#define B_ 4096
#define D_ 4000
#define K_ 6
#define Z_ 64
#define DV_ 1000   // D/4
#define EPS_ 1e-8f

typedef float f32x4 __attribute__((ext_vector_type(4)));
typedef float f32x2 __attribute__((ext_vector_type(2)));

// lgamma for x in (0, ~2]: lgamma(x) = stirling(x+4) - log(x(x+1)(x+2)(x+3))
// stirling(y) = (y-0.5)ln y - y + 0.5 ln(2pi) + 1/(12y) - 1/(360 y^3)
// abs error < ~1e-6 on the used range.
__device__ __forceinline__ float lgamma_small(float x) {
    float y = x + 4.0f;
    float p = x * (x + 1.0f) * (x + 2.0f) * (x + 3.0f);
    float ly = __logf(y);
    float r = 1.0f / y;
    float corr = r * (0.08333333333f - 0.002777777778f * (r * r));
    float stir = (y - 0.5f) * ly - y + 0.91893853320467f + corr;
    return stir - __logf(p);
}

__device__ __forceinline__ void elem(float xv, float mg, float mn, float tv,
                                     float xiv, float qv, int mk,
                                     float n0, float n1, float n2,
                                     float n3, float n4, float n5,
                                     float& s_nll, float& s_sp) {
    // spatial
    float nbm = (n0 + n1 + n2 + n3 + n4 + n5) * (1.0f / 6.0f);
    float d = qv - (xiv - nbm);
    s_sp += d * d;
    // gaussian nll (var=1, full=False): 0.5*(x-mu)^2
    float gd = xv - mg;
    float g = 0.5f * gd * gd;
    // NB log-likelihood
    float ltme = __logf(tv + mn + EPS_);
    float ll = tv * (__logf(tv + EPS_) - ltme)
             + xv * (__logf(mn + EPS_) - ltme)
             + lgamma_small(xv + tv) - lgamma_small(tv) - lgamma_small(xv + 1.0f);
    s_nll += mk ? g : -ll;
}

#define NTL(p) __builtin_nontemporal_load(&(p))

__global__ __launch_bounds__(256) void fused_row_kernel(
    const f32x4* __restrict__ x, const f32x4* __restrict__ mug,
    const f32x4* __restrict__ munb, const f32x4* __restrict__ th,
    const f32x4* __restrict__ xi, const f32x4* __restrict__ qy,
    const f32x4* __restrict__ nb, const int4* __restrict__ mask,
    const f32x2* __restrict__ muz, const f32x2* __restrict__ lvz,
    const f32x2* __restrict__ epz, f32x2* __restrict__ z,
    f32x2* __restrict__ partial)
{
    const int b = blockIdx.x;
    const int tid = threadIdx.x;
    const size_t rowv = (size_t)b * DV_;
    const f32x4* nbrow = nb + (size_t)b * (K_ * DV_);

    // reparametrize slice: 32 float2 per block (4096*32 = 131072 = B*Z/2)
    if (tid < 32) {
        const int i = b * 32 + tid;
        f32x2 m = NTL(muz[i]), l = NTL(lvz[i]), e = NTL(epz[i]);
        f32x2 r;
        r.x = m.x + e.x * __expf(0.5f * l.x);
        r.y = m.y + e.y * __expf(0.5f * l.y);
        __builtin_nontemporal_store(r, &z[i]);
    }

    float s_nll = 0.0f, s_sp = 0.0f;

    for (int j = tid; j < DV_; j += 256) {
        f32x4 xv  = NTL(x[rowv + j]);
        f32x4 mg  = NTL(mug[rowv + j]);
        f32x4 mn  = NTL(munb[rowv + j]);
        f32x4 tv  = NTL(th[rowv + j]);
        f32x4 xiv = NTL(xi[rowv + j]);
        f32x4 qv  = NTL(qy[rowv + j]);
        int4   mk = mask[j];                // reused by all blocks: keep cached
        f32x4 n0 = NTL(nbrow[0 * DV_ + j]);
        f32x4 n1 = NTL(nbrow[1 * DV_ + j]);
        f32x4 n2 = NTL(nbrow[2 * DV_ + j]);
        f32x4 n3 = NTL(nbrow[3 * DV_ + j]);
        f32x4 n4 = NTL(nbrow[4 * DV_ + j]);
        f32x4 n5 = NTL(nbrow[5 * DV_ + j]);

        elem(xv.x, mg.x, mn.x, tv.x, xiv.x, qv.x, mk.x, n0.x, n1.x, n2.x, n3.x, n4.x, n5.x, s_nll, s_sp);
        elem(xv.y, mg.y, mn.y, tv.y, xiv.y, qv.y, mk.y, n0.y, n1.y, n2.y, n3.y, n4.y, n5.y, s_nll, s_sp);
        elem(xv.z, mg.z, mn.z, tv.z, xiv.z, qv.z, mk.z, n0.z, n1.z, n2.z, n3.z, n4.z, n5.z, s_nll, s_sp);
        elem(xv.w, mg.w, mn.w, tv.w, xiv.w, qv.w, mk.w, n0.w, n1.w, n2.w, n3.w, n4.w, n5.w, s_nll, s_sp);
    }

    // wave64 reduce
    for (int off = 32; off > 0; off >>= 1) {
        s_nll += __shfl_down(s_nll, off, 64);
        s_sp  += __shfl_down(s_sp,  off, 64);
    }
    __shared__ float sa[4], sb[4];
    const int lane = tid & 63;
    const int w    = tid >> 6;
    if (lane == 0) { sa[w] = s_nll; sb[w] = s_sp; }
    __syncthreads();
    if (tid == 0) {
        f32x2 o;
        o.x = sa[0] + sa[1] + sa[2] + sa[3];
        o.y = sb[0] + sb[1] + sb[2] + sb[3];
        partial[b] = o;
    }
}

__global__ __launch_bounds__(256) void finalize_kernel(
    const f32x2* __restrict__ partial, float* __restrict__ out)
{
    __shared__ double sa[256], sb[256];
    double a = 0.0, b = 0.0;
    for (int i = threadIdx.x; i < B_; i += 256) {
        f32x2 p = partial[i];
        a += (double)p.x;
        b += (double)p.y;
    }
    sa[threadIdx.x] = a; sb[threadIdx.x] = b;
    __syncthreads();
    for (int s = 128; s > 0; s >>= 1) {
        if (threadIdx.x < s) {
            sa[threadIdx.x] += sa[threadIdx.x + s];
            sb[threadIdx.x] += sb[threadIdx.x + s];
        }
        __syncthreads();
    }
    if (threadIdx.x == 0) {
        out[0] = (float)(sa[0] / (double)B_);
        out[1] = (float)(sb[0] / ((double)B_ * (double)D_));
    }
}

extern "C" void kernel_launch(void* const* d_in, const int* in_sizes, int n_in,
                              void* d_out, int out_size, void* d_ws, size_t ws_size,
                              hipStream_t stream) {
    const f32x4* x    = (const f32x4*)d_in[0];
    const f32x4* mug  = (const f32x4*)d_in[1];
    // d_in[2] = logvar_gauss, unused by the reference
    const f32x4* munb = (const f32x4*)d_in[3];
    const f32x4* th   = (const f32x4*)d_in[4];
    const f32x4* xi   = (const f32x4*)d_in[5];
    const f32x4* nb   = (const f32x4*)d_in[6];
    const f32x4* qy   = (const f32x4*)d_in[7];
    const f32x2* muz  = (const f32x2*)d_in[8];
    const f32x2* lvz  = (const f32x2*)d_in[9];
    const f32x2* epz  = (const f32x2*)d_in[10];
    const int4*  mask = (const int4*)d_in[11];

    float* out = (float*)d_out;
    f32x2* partial = (f32x2*)d_ws;
    f32x2* z = (f32x2*)(out + 2);

    fused_row_kernel<<<B_, 256, 0, stream>>>(x, mug, munb, th, xi, qy, nb, mask,
                                             muz, lvz, epz, z, partial);
    finalize_kernel<<<1, 256, 0, stream>>>(partial, out);
}